// Round 1
// baseline (537.696 us; speedup 1.0000x reference)
//
#include <hip/hip_runtime.h>
#include <math.h>

#ifndef __has_builtin
#define __has_builtin(x) 0
#endif

#define S_LEN 2048
#define B_N   4096

__device__ __forceinline__ float hw_exp2(float x) { return __builtin_amdgcn_exp2f(x); }
__device__ __forceinline__ float hw_rcp(float x)  { return __builtin_amdgcn_rcpf(x); }

// lane l <- lane (l ^ 4): same gate, unit m^1 (within 16-lane chain group)
__device__ __forceinline__ float swz_xor4(float v) {
    return __int_as_float(__builtin_amdgcn_ds_swizzle(__float_as_int(v), 0x101F));
}
// lane l <- lane (l ^ 8): same gate, unit m^2
__device__ __forceinline__ float swz_xor8(float v) {
    return __int_as_float(__builtin_amdgcn_ds_swizzle(__float_as_int(v), 0x201F));
}

// broadcast quad-lane K (gate K) to all 4 lanes of the quad (quad == unit)
template<int K>
__device__ __forceinline__ float quad_bcast(float v) {
#if __has_builtin(__builtin_amdgcn_mov_dpp)
    return __int_as_float(__builtin_amdgcn_mov_dpp(__float_as_int(v), K * 0x55, 0xF, 0xF, false));
#else
    return __int_as_float(__builtin_amdgcn_ds_swizzle(__float_as_int(v), 0x8000 | (K * 0x55)));
#endif
}

// Gate activation. Weights for this lane's row were prescaled by
//   s = -log2(e)      (sigmoid gates i,f,o)  -> sigmoid(x) = rcp(1 + exp2(z))
//   s = -2*log2(e)    (cell gate g)          -> tanh(x) = sign(-z)*(1-e)/(1+e), e = exp2(-|z|)
__device__ __forceinline__ float act_gate(float z, bool is_tanh) {
    float zz = is_tanh ? -fabsf(z) : z;
    float e  = hw_exp2(zz);
    float r  = hw_rcp(1.0f + e);
    float th = (1.0f - e) * r;
    th = copysignf(th, -z);
    return is_tanh ? th : r;
}

// tanh(c), overflow-safe for any |c| (e in (0,1])
__device__ __forceinline__ float tanh_from_c(float c) {
    const float N2LOG2E = -2.8853900817779268f; // -2*log2(e)
    float e = hw_exp2(fabsf(c) * N2LOG2E);
    float r = hw_rcp(1.0f + e);
    return copysignf((1.0f - e) * r, c);
}

__global__ __launch_bounds__(256) void lstm2_kernel(
    const float* __restrict__ X,
    const float* __restrict__ Wih0, const float* __restrict__ Whh0,
    const float* __restrict__ bih0, const float* __restrict__ bhh0,
    const float* __restrict__ Wih1, const float* __restrict__ Whh1,
    const float* __restrict__ bih1, const float* __restrict__ bhh1,
    const float* __restrict__ Wout, const float* __restrict__ bOut,
    float* __restrict__ Y)
{
    const int tid = blockIdx.x * blockDim.x + threadIdx.x;
    const int b   = tid >> 4;        // batch chain, 16 lanes each
    const int l16 = tid & 15;
    const int m   = l16 >> 2;        // hidden unit (quad index)
    const int g   = l16 & 3;         // gate: 0=i 1=f 2=g 3=o
    const int j   = g * 4 + m;       // row in the (4H) stacked weight layout

    const float LOG2E = 1.4426950408889634f;
    const bool  is_tanh = (g == 2);
    const float s = is_tanh ? (-2.0f * LOG2E) : (-LOG2E);

    // preload + prescale weights (per-lane, once)
    const float a0    = Wih0[j] * s;                 // (16,1)
    const float bias0 = (bih0[j] + bhh0[j]) * s;
    const float bias1 = (bih1[j] + bhh1[j]) * s;
    float U0[4], Wi1[4], U1[4], wop[4];
    #pragma unroll
    for (int d = 0; d < 4; ++d) {
        const int k = m ^ d;                         // column matching h?v[d]'s unit
        U0[d]  = Whh0[j * 4 + k] * s;
        Wi1[d] = Wih1[j * 4 + k] * s;
        U1[d]  = Whh1[j * 4 + k] * s;
        wop[d] = Wout[k];
    }
    const float bo = bOut[0];

    // state: each lane carries its unit's c (redundant x4 within quad),
    // plus the full broadcast h vectors of both layers
    float c1 = 0.f, c2 = 0.f;
    float h1v0 = 0.f, h1v1 = 0.f, h1v2 = 0.f, h1v3 = 0.f;
    float h2v0 = 0.f, h2v1 = 0.f, h2v2 = 0.f, h2v3 = 0.f;

    const float* xp = X + b;
    float*       yp = Y + b;

    // x prefetch ring, depth 8 (hides HBM latency under ~8 steps of compute)
    float xbuf[8];
    #pragma unroll
    for (int u = 0; u < 8; ++u) xbuf[u] = xp[u * B_N];

    for (int t0 = 0; t0 < S_LEN; t0 += 8) {
        #pragma unroll
        for (int u = 0; u < 8; ++u) {
            const int t = t0 + u;
            const float x = xbuf[u];
            const int tn = (t + 8 < S_LEN) ? (t + 8) : (S_LEN - 1);
            xbuf[u] = xp[tn * B_N];

            // ---------- layer 0 ----------
            float z = fmaf(x, a0, bias0);
            z = fmaf(U0[0], h1v0, z);
            z = fmaf(U0[1], h1v1, z);
            z = fmaf(U0[2], h1v2, z);
            z = fmaf(U0[3], h1v3, z);
            const float v0 = act_gate(z, is_tanh);

            const float iv0 = quad_bcast<0>(v0);
            const float fv0 = quad_bcast<1>(v0);
            const float gv0 = quad_bcast<2>(v0);
            const float ov0 = quad_bcast<3>(v0);
            c1 = fmaf(fv0, c1, iv0 * gv0);
            const float h1 = ov0 * tanh_from_c(c1);

            h1v0 = h1;
            h1v1 = swz_xor4(h1);
            h1v2 = swz_xor8(h1);
            h1v3 = swz_xor8(h1v1);

            // ---------- layer 1 ----------
            float z1 = bias1;
            z1 = fmaf(Wi1[0], h1v0, z1);
            z1 = fmaf(Wi1[1], h1v1, z1);
            z1 = fmaf(Wi1[2], h1v2, z1);
            z1 = fmaf(Wi1[3], h1v3, z1);
            z1 = fmaf(U1[0], h2v0, z1);
            z1 = fmaf(U1[1], h2v1, z1);
            z1 = fmaf(U1[2], h2v2, z1);
            z1 = fmaf(U1[3], h2v3, z1);
            const float v1 = act_gate(z1, is_tanh);

            const float iv1 = quad_bcast<0>(v1);
            const float fv1 = quad_bcast<1>(v1);
            const float gv1 = quad_bcast<2>(v1);
            const float ov1 = quad_bcast<3>(v1);
            c2 = fmaf(fv1, c2, iv1 * gv1);
            const float h2 = ov1 * tanh_from_c(c2);

            h2v0 = h2;
            h2v1 = swz_xor4(h2);
            h2v2 = swz_xor8(h2);
            h2v3 = swz_xor8(h2v1);

            // ---------- output projection (reuses broadcast h2) ----------
            float y = bo;
            y = fmaf(wop[0], h2v0, y);
            y = fmaf(wop[1], h2v1, y);
            y = fmaf(wop[2], h2v2, y);
            y = fmaf(wop[3], h2v3, y);
            if (l16 == 0) yp[t * B_N] = y;
        }
    }
}

extern "C" void kernel_launch(void* const* d_in, const int* in_sizes, int n_in,
                              void* d_out, int out_size, void* d_ws, size_t ws_size,
                              hipStream_t stream) {
    const float* X    = (const float*)d_in[0];
    const float* Wih0 = (const float*)d_in[1];
    const float* Whh0 = (const float*)d_in[2];
    const float* bih0 = (const float*)d_in[3];
    const float* bhh0 = (const float*)d_in[4];
    const float* Wih1 = (const float*)d_in[5];
    const float* Whh1 = (const float*)d_in[6];
    const float* bih1 = (const float*)d_in[7];
    const float* bhh1 = (const float*)d_in[8];
    const float* Wout = (const float*)d_in[9];
    const float* bOut = (const float*)d_in[10];
    float* Y = (float*)d_out;

    // 4096 chains x 16 lanes = 65536 threads = 1024 waves = 1 wave/SIMD chip-wide
    dim3 grid(256), block(256);
    hipLaunchKernelGGL(lstm2_kernel, grid, block, 0, stream,
                       X, Wih0, Whh0, bih0, bhh0, Wih1, Whh1, bih1, bhh1, Wout, bOut, Y);
}

// Round 2
// 415.495 us; speedup vs baseline: 1.2941x; 1.2941x over previous
//
#include <hip/hip_runtime.h>
#include <math.h>

#ifndef __has_builtin
#define __has_builtin(x) 0
#endif

#define S_LEN 2048
#define B_N   4096

__device__ __forceinline__ float hw_exp2(float x) { return __builtin_amdgcn_exp2f(x); }
__device__ __forceinline__ float hw_rcp(float x)  { return __builtin_amdgcn_rcpf(x); }

// Generic DPP move (ctrl is a compile-time constant).
// All ctrls used here are involutions (or symmetric rotations), so there is
// no shift-direction ambiguity:
//   0x55*K      : quad_perm broadcast lane K of each quad
//   0x1B        : quad_perm [3,2,1,0]  == lane ^ 3
//   0x128       : row_ror:8           == lane ^ 8 (rotation by half-row)
//   0x141       : row_half_mirror     == lane ^ 7
template<int CTRL>
__device__ __forceinline__ float dpp_mov(float v) {
    return __int_as_float(__builtin_amdgcn_mov_dpp(__float_as_int(v), CTRL, 0xF, 0xF, false));
}

// broadcast quad-lane K (gate K) to all 4 lanes of the quad (quad == unit)
template<int K>
__device__ __forceinline__ float quad_bcast(float v) {
    return dpp_mov<K * 0x55>(v);
}

// tanh(c) = 1 - 2/(1 + exp(2c)), overflow-safe (exp2->inf => rcp->0 => 1)
__device__ __forceinline__ float tanh_c(float c) {
    const float TWO_LOG2E = 2.8853900817779268f;
    float e = hw_exp2(c * TWO_LOG2E);
    float r = hw_rcp(1.0f + e);
    return fmaf(-2.0f, r, 1.0f);
}

__global__ __launch_bounds__(256) void lstm2_kernel(
    const float* __restrict__ X,
    const float* __restrict__ Wih0, const float* __restrict__ Whh0,
    const float* __restrict__ bih0, const float* __restrict__ bhh0,
    const float* __restrict__ Wih1, const float* __restrict__ Whh1,
    const float* __restrict__ bih1, const float* __restrict__ bhh1,
    const float* __restrict__ Wout, const float* __restrict__ bOut,
    float* __restrict__ Y)
{
    const int tid = blockIdx.x * blockDim.x + threadIdx.x;
    const int b   = tid >> 4;        // batch chain, 16 lanes each
    const int l16 = tid & 15;
    const int m   = l16 >> 2;        // hidden unit (quad index)
    const int g   = l16 & 3;         // gate: 0=i 1=f 2=g 3=o
    const int j   = g * 4 + m;       // row in the (4H) stacked weight layout

    const float LOG2E = 1.4426950408889634f;
    const bool  is_tanh = (g == 2);
    // sigmoid rows: z = -log2e * pre;  sigmoid = rcp(1+exp2(z))
    // tanh rows:    z = +2*log2e * pre; tanh    = 1 - 2*rcp(1+exp2(z))
    const float s  = is_tanh ? (2.0f * LOG2E) : (-LOG2E);
    const float ka = is_tanh ? -2.0f : 1.0f;
    const float kb = is_tanh ?  1.0f : 0.0f;

    // preload + prescale weights (per-lane, once)
    const float a0    = Wih0[j] * s;                 // (16,1)
    const float bias0 = (bih0[j] + bhh0[j]) * s;
    const float bias1 = (bih1[j] + bhh1[j]) * s;
    float U0[4], Wi1[4], U1[4], wop[4];
    #pragma unroll
    for (int d = 0; d < 4; ++d) {
        const int k = m ^ d;                         // column matching h?v[d]'s unit
        U0[d]  = Whh0[j * 4 + k] * s;
        Wi1[d] = Wih1[j * 4 + k] * s;
        U1[d]  = Whh1[j * 4 + k] * s;
        wop[d] = Wout[k];
    }
    const float bo = bOut[0];

    // state: each lane carries its unit's c (redundant x4 within quad),
    // plus the full broadcast h vectors of both layers (hXv[d] = h[m^d])
    float c1 = 0.f, c2 = 0.f;
    float h1v0 = 0.f, h1v1 = 0.f, h1v2 = 0.f, h1v3 = 0.f;
    float h2v0 = 0.f, h2v1 = 0.f, h2v2 = 0.f, h2v3 = 0.f;

    const float* xp = X + b;
    float*       yp = Y + b;

    // x prefetch ring, depth 8 (hides HBM latency under ~8 steps of compute)
    float xbuf[8];
    #pragma unroll
    for (int u = 0; u < 8; ++u) xbuf[u] = xp[u * B_N];

    for (int t0 = 0; t0 < S_LEN; t0 += 8) {
        #pragma unroll
        for (int u = 0; u < 8; ++u) {
            const int t = t0 + u;
            const float x = xbuf[u];
            const int tn = (t + 8 < S_LEN) ? (t + 8) : (S_LEN - 1);
            xbuf[u] = xp[tn * B_N];

            // ---------- layer 0 ----------
            float p0 = fmaf(x, a0, bias0);
            p0 = fmaf(U0[0], h1v0, p0);
            p0 = fmaf(U0[1], h1v1, p0);
            float p1 = fmaf(U0[3], h1v3, U0[2] * h1v2);
            float z  = p0 + p1;
            float e0 = hw_exp2(z);
            float r0 = hw_rcp(1.0f + e0);
            float v0 = fmaf(ka, r0, kb);

            const float iv0 = quad_bcast<0>(v0);
            const float fv0 = quad_bcast<1>(v0);
            const float gv0 = quad_bcast<2>(v0);
            const float ov0 = quad_bcast<3>(v0);
            c1 = fmaf(fv0, c1, iv0 * gv0);
            const float h1 = ov0 * tanh_c(c1);

            h1v0 = h1;
            h1v1 = dpp_mov<0x1B>(dpp_mov<0x141>(h1)); // xor7 then xor3 => xor4
            h1v2 = dpp_mov<0x128>(h1);                // xor8
            h1v3 = dpp_mov<0x128>(h1v1);              // xor8 of xor4 => xor12

            // ---------- layer 1 ----------
            float q0 = fmaf(Wi1[0], h1v0, bias1);
            q0 = fmaf(Wi1[1], h1v1, q0);
            float q1 = fmaf(Wi1[3], h1v3, Wi1[2] * h1v2);
            float q2 = fmaf(U1[1], h2v1, U1[0] * h2v0);   // depends only on prev h2
            float q3 = fmaf(U1[3], h2v3, U1[2] * h2v2);
            float z1 = (q0 + q1) + (q2 + q3);
            float e1 = hw_exp2(z1);
            float r1 = hw_rcp(1.0f + e1);
            float v1 = fmaf(ka, r1, kb);

            const float iv1 = quad_bcast<0>(v1);
            const float fv1 = quad_bcast<1>(v1);
            const float gv1 = quad_bcast<2>(v1);
            const float ov1 = quad_bcast<3>(v1);
            c2 = fmaf(fv1, c2, iv1 * gv1);
            const float h2 = ov1 * tanh_c(c2);

            h2v0 = h2;
            h2v1 = dpp_mov<0x1B>(dpp_mov<0x141>(h2)); // xor4
            h2v2 = dpp_mov<0x128>(h2);                // xor8
            h2v3 = dpp_mov<0x128>(h2v1);              // xor12

            // ---------- output projection (reuses broadcast h2) ----------
            float y = fmaf(wop[0], h2v0, bo);
            y = fmaf(wop[1], h2v1, y);
            y = fmaf(wop[2], h2v2, y);
            y = fmaf(wop[3], h2v3, y);
            if (l16 == 0) yp[t * B_N] = y;
        }
    }
}

extern "C" void kernel_launch(void* const* d_in, const int* in_sizes, int n_in,
                              void* d_out, int out_size, void* d_ws, size_t ws_size,
                              hipStream_t stream) {
    const float* X    = (const float*)d_in[0];
    const float* Wih0 = (const float*)d_in[1];
    const float* Whh0 = (const float*)d_in[2];
    const float* bih0 = (const float*)d_in[3];
    const float* bhh0 = (const float*)d_in[4];
    const float* Wih1 = (const float*)d_in[5];
    const float* Whh1 = (const float*)d_in[6];
    const float* bih1 = (const float*)d_in[7];
    const float* bhh1 = (const float*)d_in[8];
    const float* Wout = (const float*)d_in[9];
    const float* bOut = (const float*)d_in[10];
    float* Y = (float*)d_out;

    // 4096 chains x 16 lanes = 65536 threads = 1024 waves = 1 wave/SIMD chip-wide
    dim3 grid(256), block(256);
    hipLaunchKernelGGL(lstm2_kernel, grid, block, 0, stream,
                       X, Wih0, Whh0, bih0, bhh0, Wih1, Whh1, bih1, bhh1, Wout, bOut, Y);
}

// Round 3
// 333.737 us; speedup vs baseline: 1.6111x; 1.2450x over previous
//
#include <hip/hip_runtime.h>
#include <math.h>

#ifndef __has_builtin
#define __has_builtin(x) 0
#endif

#define S_LEN 2048
#define B_N   4096

__device__ __forceinline__ float hw_exp2(float x) { return __builtin_amdgcn_exp2f(x); }
__device__ __forceinline__ float hw_rcp(float x)  { return __builtin_amdgcn_rcpf(x); }

// Generic DPP move (ctrl is a compile-time constant). All ctrls used are
// involutions -> no shift-direction ambiguity:
//   0x55*K : quad_perm broadcast lane K of each quad
//   0x1B   : quad_perm [3,2,1,0]  == lane ^ 3
//   0x128  : row_ror:8            == lane ^ 8 (rotation by half-row)
//   0x141  : row_half_mirror      == lane ^ 7
template<int CTRL>
__device__ __forceinline__ float dpp_mov(float v) {
    return __int_as_float(__builtin_amdgcn_mov_dpp(__float_as_int(v), CTRL, 0xF, 0xF, false));
}
template<int K>
__device__ __forceinline__ float quad_bcast(float v) { return dpp_mov<K * 0x55>(v); }

// tanh(c) = 1 - 2/(1 + exp(2c)), overflow-safe (exp2->inf => rcp->0 => 1)
__device__ __forceinline__ float tanh_c(float c) {
    const float TWO_LOG2E = 2.8853900817779268f;
    float e = hw_exp2(c * TWO_LOG2E);
    float r = hw_rcp(1.0f + e);
    return fmaf(-2.0f, r, 1.0f);
}

__global__ __launch_bounds__(256) void lstm2_kernel(
    const float* __restrict__ X,
    const float* __restrict__ Wih0, const float* __restrict__ Whh0,
    const float* __restrict__ bih0, const float* __restrict__ bhh0,
    const float* __restrict__ Wih1, const float* __restrict__ Whh1,
    const float* __restrict__ bih1, const float* __restrict__ bhh1,
    const float* __restrict__ Wout, const float* __restrict__ bOut,
    float* __restrict__ Y)
{
    const int tid = blockIdx.x * blockDim.x + threadIdx.x;
    const int b   = tid >> 4;        // batch chain, 16 lanes each
    const int l16 = tid & 15;
    const int m   = l16 >> 2;        // hidden unit (quad index)
    const int g   = l16 & 3;         // gate: 0=i 1=f 2=g 3=o
    const int j   = g * 4 + m;       // row in the (4H) stacked weight layout

    const float LOG2E = 1.4426950408889634f;
    const bool  is_tanh = (g == 2);
    // sigmoid rows: z = -log2e * pre;  sigmoid = rcp(1+exp2(z))
    // tanh rows:    z = +2*log2e * pre; tanh    = 1 - 2*rcp(1+exp2(z))
    const float s  = is_tanh ? (2.0f * LOG2E) : (-LOG2E);
    const float ka = is_tanh ? -2.0f : 1.0f;
    const float kb = is_tanh ?  1.0f : 0.0f;

    // preload + prescale weights (per-lane, once)
    const float a0    = Wih0[j] * s;                 // (16,1)
    const float bias0 = (bih0[j] + bhh0[j]) * s;
    const float bias1 = (bih1[j] + bhh1[j]) * s;
    float U0[4], Wi1[4], U1[4], wop[4];
    #pragma unroll
    for (int d = 0; d < 4; ++d) {
        const int k = m ^ d;                         // column matching h?v[d]'s unit
        U0[d]  = Whh0[j * 4 + k] * s;
        Wi1[d] = Wih1[j * 4 + k] * s;
        U1[d]  = Whh1[j * 4 + k] * s;
        wop[d] = Wout[k];
    }
    const float bo = bOut[0];

    // state (hXv[d] = hX[m^d] broadcast vectors):
    //   at entry of iteration t: h1v = h1(t-1), c1 = c1(t-1),
    //                            h2v = h2(t-2), c2 = c2(t-2)
    float c1 = 0.f, c2 = 0.f;
    float h1v0 = 0.f, h1v1 = 0.f, h1v2 = 0.f, h1v3 = 0.f;
    float h2v0 = 0.f, h2v1 = 0.f, h2v2 = 0.f, h2v3 = 0.f;

    const float* xp = X + b;
    float*       yp = Y + b;

    // x prefetch ring, depth 8
    float xbuf[8];
    #pragma unroll
    for (int u = 0; u < 8; ++u) xbuf[u] = xp[u * B_N];

    float ybuf[8];

    // layer-1 step t-1: consumes OLD h1v (= h1(t-1)) and h2v (= h2(t-2)),
    // commits h2v/c2, emits y(t-1)
    auto L1 = [&](float& yout) {
        float q0 = fmaf(Wi1[0], h1v0, bias1);
        q0 = fmaf(Wi1[1], h1v1, q0);
        float q1 = fmaf(Wi1[3], h1v3, Wi1[2] * h1v2);
        float q2 = fmaf(U1[1], h2v1, U1[0] * h2v0);
        float q3 = fmaf(U1[3], h2v3, U1[2] * h2v2);
        float z1 = (q0 + q1) + (q2 + q3);
        float r1 = hw_rcp(1.0f + hw_exp2(z1));
        float v1 = fmaf(ka, r1, kb);
        float iv1 = quad_bcast<0>(v1), fv1 = quad_bcast<1>(v1);
        float gv1 = quad_bcast<2>(v1), ov1 = quad_bcast<3>(v1);
        c2 = fmaf(fv1, c2, iv1 * gv1);
        float h2 = ov1 * tanh_c(c2);
        float n20 = h2;
        float n21 = dpp_mov<0x1B>(dpp_mov<0x141>(h2)); // xor4
        float n22 = dpp_mov<0x128>(h2);                // xor8
        float n23 = dpp_mov<0x128>(n21);               // xor12
        float y = fmaf(wop[0], n20, bo);
        y = fmaf(wop[1], n21, y);
        y = fmaf(wop[2], n22, y);
        y = fmaf(wop[3], n23, y);
        yout = y;
        h2v0 = n20; h2v1 = n21; h2v2 = n22; h2v3 = n23;
    };

    // layer-0 step t: consumes OLD h1v (= h1(t-1)); new h1 returned via n1*
    // (commit deferred so L1 in the same iteration still sees h1(t-1))
    auto sub = [&](float x, bool doL1, float& yout) {
        float p0 = fmaf(x, a0, bias0);
        p0 = fmaf(U0[0], h1v0, p0);
        p0 = fmaf(U0[1], h1v1, p0);
        float p1 = fmaf(U0[3], h1v3, U0[2] * h1v2);
        float z  = p0 + p1;
        float r0 = hw_rcp(1.0f + hw_exp2(z));
        float v0 = fmaf(ka, r0, kb);
        float iv0 = quad_bcast<0>(v0), fv0 = quad_bcast<1>(v0);
        float gv0 = quad_bcast<2>(v0), ov0 = quad_bcast<3>(v0);
        c1 = fmaf(fv0, c1, iv0 * gv0);
        float h1 = ov0 * tanh_c(c1);
        float n10 = h1;
        float n11 = dpp_mov<0x1B>(dpp_mov<0x141>(h1)); // xor4
        float n12 = dpp_mov<0x128>(h1);                // xor8
        float n13 = dpp_mov<0x128>(n11);               // xor12

        if (doL1) L1(yout);                            // independent of L0 above

        h1v0 = n10; h1v1 = n11; h1v2 = n12; h1v3 = n13;
    };

    // ---- first block (t = 0..7): peel L1 at t=0 ----
    {
        float dummy;
        #pragma unroll
        for (int u = 0; u < 8; ++u) {
            float x = xbuf[u];
            xbuf[u] = xp[(u + 8) * B_N];
            if (u == 0) sub(x, false, dummy);
            else        sub(x, true, ybuf[u]);
        }
        if (l16 == 0) {
            #pragma unroll
            for (int u = 1; u < 8; ++u) yp[(u - 1) * B_N] = ybuf[u];
        }
    }

    // ---- main blocks (t = 8..2047), L1 covers t-1 = 7..2046 ----
    for (int t0 = 8; t0 < S_LEN; t0 += 8) {
        #pragma unroll
        for (int u = 0; u < 8; ++u) {
            const int t = t0 + u;
            float x = xbuf[u];
            int tn = t + 8; if (tn > S_LEN - 1) tn = S_LEN - 1;
            xbuf[u] = xp[tn * B_N];
            sub(x, true, ybuf[u]);
        }
        if (l16 == 0) {
            #pragma unroll
            for (int u = 0; u < 8; ++u) yp[(t0 - 1 + u) * B_N] = ybuf[u];
        }
    }

    // ---- epilogue: final L1 step t = 2047 ----
    {
        float yfin;
        L1(yfin);
        if (l16 == 0) yp[(S_LEN - 1) * B_N] = yfin;
    }
}

extern "C" void kernel_launch(void* const* d_in, const int* in_sizes, int n_in,
                              void* d_out, int out_size, void* d_ws, size_t ws_size,
                              hipStream_t stream) {
    const float* X    = (const float*)d_in[0];
    const float* Wih0 = (const float*)d_in[1];
    const float* Whh0 = (const float*)d_in[2];
    const float* bih0 = (const float*)d_in[3];
    const float* bhh0 = (const float*)d_in[4];
    const float* Wih1 = (const float*)d_in[5];
    const float* Whh1 = (const float*)d_in[6];
    const float* bih1 = (const float*)d_in[7];
    const float* bhh1 = (const float*)d_in[8];
    const float* Wout = (const float*)d_in[9];
    const float* bOut = (const float*)d_in[10];
    float* Y = (float*)d_out;

    // 4096 chains x 16 lanes = 65536 threads = 1024 waves = 1 wave/SIMD chip-wide
    dim3 grid(256), block(256);
    hipLaunchKernelGGL(lstm2_kernel, grid, block, 0, stream,
                       X, Wih0, Whh0, bih0, bhh0, Wih1, Whh1, bih1, bhh1, Wout, bOut, Y);
}